// Round 9
// baseline (215.677 us; speedup 1.0000x reference)
//
#include <hip/hip_runtime.h>

#define CIN   32
#define COUT  64
#define K_OFF 27

typedef __attribute__((ext_vector_type(8))) short bf16x8;
typedef __attribute__((ext_vector_type(4))) float f32x4;

// exact vmcnt fence + compiler memory pin (defines VMEM issue order)
#define FENCE_VM(N) asm volatile("s_waitcnt vmcnt(" #N ")" ::: "memory")
#define PIN()       asm volatile("" ::: "memory")

__device__ inline unsigned short f2bf_rne(float f) {
    union { float f; unsigned int u; } v; v.f = f;
    unsigned int u = v.u;
    u = (u + 0x7fffu + ((u >> 16) & 1u)) >> 16;
    return (unsigned short)u;
}

// async 16B global -> LDS (per-lane src addr; LDS dest = wave-uniform base
// + lane*16). Completion signaled via vmcnt — fenced by hand.
__device__ inline void async_load16(const void* g, void* l) {
    __builtin_amdgcn_global_load_lds(
        (const __attribute__((address_space(1))) void*)g,
        (__attribute__((address_space(3))) void*)l, 16, 0, 0);
}

// ===========================================================================
// prep_all — ONE grid-stride kernel (banked R7): per-block mask-dtype detect;
// feat fp32->bf16; midx; wt2 repack; zrow.
// ===========================================================================
__global__ __launch_bounds__(256) void prep_all(
    const float* __restrict__ feat, const int* __restrict__ nmap,
    const unsigned char* __restrict__ mask8, const float* __restrict__ wk,
    unsigned short* __restrict__ featb, int* __restrict__ midx,
    unsigned short* __restrict__ wt2, float* __restrict__ zrow,
    int n, int det_bytes)
{
    __shared__ int wany[4];
    const int tid = threadIdx.x;
    const int gsz = gridDim.x * 256;
    const int gt  = blockIdx.x * 256 + tid;

    // per-block detect: nonzero byte at a non-dword-aligned offset => b8 mask
    {
        int found = 0;
        for (int i = tid; i < det_bytes; i += 256)
            if ((i & 3) && mask8[i]) found = 1;
        unsigned long long b = __ballot(found);
        if ((tid & 63) == 0) wany[tid >> 6] = b ? 1 : 0;
        __syncthreads();
    }
    const int is_b8 = wany[0] | wany[1] | wany[2] | wany[3];

    // feat fp32 -> bf16
    const int F = (n * CIN) / 8;
    for (int i = gt; i < F; i += gsz) {
        const int base = i * 8;
        float4 a = *(const float4*)(feat + base);
        float4 b = *(const float4*)(feat + base + 4);
        bf16x8 v;
        v[0] = (short)f2bf_rne(a.x); v[1] = (short)f2bf_rne(a.y);
        v[2] = (short)f2bf_rne(a.z); v[3] = (short)f2bf_rne(a.w);
        v[4] = (short)f2bf_rne(b.x); v[5] = (short)f2bf_rne(b.y);
        v[6] = (short)f2bf_rne(b.z); v[7] = (short)f2bf_rne(b.w);
        *(bf16x8*)(featb + base) = v;
    }

    // midx = mask ? nmap : -1
    {
        const int total = K_OFF * n;
        const int Q = (total + 3) / 4;
        for (int i = gt; i < Q; i += gsz) {
            int e = i * 4;
            if (e + 3 < total) {
                int4 nm = *(const int4*)(nmap + e);
                int m0, m1, m2, m3;
                if (is_b8) {
                    uchar4 mb = *(const uchar4*)(mask8 + e);
                    m0 = mb.x; m1 = mb.y; m2 = mb.z; m3 = mb.w;
                } else {
                    const int* m32 = (const int*)mask8;
                    int4 mm = *(const int4*)(m32 + e);
                    m0 = mm.x; m1 = mm.y; m2 = mm.z; m3 = mm.w;
                }
                int4 r;
                r.x = m0 ? nm.x : -1; r.y = m1 ? nm.y : -1;
                r.z = m2 ? nm.z : -1; r.w = m3 ? nm.w : -1;
                *(int4*)(midx + e) = r;
            } else {
                for (; e < total; ++e) {
                    int m = is_b8 ? (int)mask8[e] : ((const int*)mask8)[e];
                    midx[e] = m ? nmap[e] : -1;
                }
            }
        }
    }

    // weights -> fragment-order bf16 wt2[k][ct][lane][8]
    for (int t = gt; t < K_OFF * 4 * 64; t += gsz) {
        const int lane = t & 63, ct = (t >> 6) & 3, k = t >> 8;
        const int lrow = lane & 15, q = lane >> 4;
        const int col = ct * 16 + lrow;
        bf16x8 v;
        #pragma unroll
        for (int j = 0; j < 8; ++j)
            v[j] = (short)f2bf_rne(wk[(k * CIN + q * 8 + j) * COUT + col]);
        *(bf16x8*)(wt2 + t * 8) = v;
    }

    if (gt < 16) zrow[gt] = 0.0f;
}

// ---------------------------------------------------------------------------
// conv_mfma15 — BARRIER-FREE waves (convoy-effect test).
// R8 lesson: resident waves = the latency-hiding resource; R0's residual
// stall theory: 4 barrier-locked waves/block advance at the SLOWEST wave's
// gather (max-of-4 tail amplification). Here each wave is fully independent:
//   * As stays per-wave (3-slot ring, 24KB/block total) — same G/M schedule
//     and slack as R0.
//   * B fragments -> per-wave REGISTERS (4x bf16x8 loads/body, issued 2
//     bodies ahead; wt2 = 55KB, L2-resident, so 4x re-read is cheap).
//   * NO s_barrier anywhere. LDS 36.9->24KB. __launch_bounds__(256,4) pins
//     VGPR <= 128 (4 waves/SIMD -> 16 waves/CU static, same as R0).
// Per-body VMEM (pinned order): [B(k+2)x4][G(k+2)x2][M(k+4)x2] = 8 ops.
// Fence walk (end of body k retires G(k+1), issued body k-1 pos 5-6):
//   younger = M(k+3)x2 [body k-1 pos 7-8] + body k's 8 = 10 (steady).
//   prologue: M(0..3)x2=8, B(0)x4,B(1)x4, G(0)x2, G(1)x2 -> FENCE_VM(2).
//   k=0: younger = body0's 8 -> 8.   k=1..22: 10.
//   k=23: M(26)x2 + B(25)x4,G(25)x2 -> 8.   k=24: B(26)x4,G(26)x2 -> 6.
//   k=25: 0.   k=26: none.
// Compiler auto-waits for B(k)/M(k+2) registers are no-ops: both are OLDER
// than the G retired by the previous body's fence.
// ---------------------------------------------------------------------------
__global__ __launch_bounds__(256, 4) void conv_mfma15(
    const unsigned short* __restrict__ featb,   // [N][CIN] bf16
    const int*            __restrict__ midx,    // [K][N] fused mask?nmap:-1
    const unsigned short* __restrict__ wt2,     // fragment-order weights
    const unsigned short* __restrict__ zrow,    // 64B of zeros
    float* __restrict__ out, int n)
{
    __shared__ __attribute__((aligned(16))) unsigned short As[3][4][2][512]; // 24 KB

    const int tid  = threadIdx.x;
    const int wave = tid >> 6;
    const int lane = tid & 63;
    const int lrow = lane & 15;
    const int q    = lane >> 4;
    const int n0   = blockIdx.x * 128 + wave * 32;

    const int  row0 = n0 + lrow, row1 = n0 + 16 + lrow;
    const bool vr0 = row0 < n, vr1 = row1 < n;

    auto load_mi = [&](int k, int rt) -> int {
        const int  r = rt ? row1 : row0;
        const bool v = rt ? vr1 : vr0;
        if (!v) return -1;
        return midx[k * n + r];
    };
    auto issue_gather = [&](int mi, unsigned short* ldsbase) {
        const unsigned short* src =
            (mi >= 0) ? featb + (size_t)mi * CIN + q * 8 : zrow;
        async_load16(src, ldsbase);
    };
    auto loadB = [&](int k, int j) -> bf16x8 {   // quarter j of slice k
        return *(const bf16x8*)(wt2 + (((k * 4 + j)) << 9) + lane * 8);
    };

    int    mi_buf[2][2];
    bf16x8 bfr[2][4];
    f32x4  acc[2][4] = {};

    // ---- prologue: M(0..3); B(0),B(1) regs; G(0),G(1). FENCE_VM(2): G(1)x2 fly.
    {
        int p00 = load_mi(0, 0), p01 = load_mi(0, 1);
        int p10 = load_mi(1, 0), p11 = load_mi(1, 1);
        mi_buf[0][0] = load_mi(2, 0); mi_buf[0][1] = load_mi(2, 1);
        mi_buf[1][0] = load_mi(3, 0); mi_buf[1][1] = load_mi(3, 1);
        PIN();
        #pragma unroll
        for (int j = 0; j < 4; ++j) bfr[0][j] = loadB(0, j);
        #pragma unroll
        for (int j = 0; j < 4; ++j) bfr[1][j] = loadB(1, j);
        PIN();
        issue_gather(p00, &As[0][wave][0][0]);
        issue_gather(p01, &As[0][wave][1][0]);
        PIN();
        issue_gather(p10, &As[1][wave][0][0]);
        issue_gather(p11, &As[1][wave][1][0]);
        PIN();
        FENCE_VM(2);    // retire M's, B-regs, G(0)x2; G(1)x2 in flight
    }

    #pragma unroll
    for (int k = 0; k < K_OFF; ++k) {
        // ---- consume LDS (own-wave fence at end of previous body) + B regs
        bf16x8 a0 = *(const bf16x8*)(&As[k % 3][wave][0][lane * 8]);
        bf16x8 a1 = *(const bf16x8*)(&As[k % 3][wave][1][lane * 8]);
        bf16x8 b0 = bfr[k & 1][0];
        bf16x8 b1 = bfr[k & 1][1];
        bf16x8 b2 = bfr[k & 1][2];
        bf16x8 b3 = bfr[k & 1][3];
        PIN();

        // ---- prefetch issues (pinned order: B-regs, G, M)
        if (k + 2 < K_OFF) {
            #pragma unroll
            for (int j = 0; j < 4; ++j) bfr[k & 1][j] = loadB(k + 2, j);
            PIN();
            issue_gather(mi_buf[k & 1][0], &As[(k + 2) % 3][wave][0][0]);
            issue_gather(mi_buf[k & 1][1], &As[(k + 2) % 3][wave][1][0]);
            PIN();
        }
        if (k + 4 < K_OFF) {
            mi_buf[k & 1][0] = load_mi(k + 4, 0);
            mi_buf[k & 1][1] = load_mi(k + 4, 1);
            PIN();
        }

        // ---- 8 MFMA
        acc[0][0] = __builtin_amdgcn_mfma_f32_16x16x32_bf16(a0, b0, acc[0][0], 0, 0, 0);
        acc[1][0] = __builtin_amdgcn_mfma_f32_16x16x32_bf16(a1, b0, acc[1][0], 0, 0, 0);
        acc[0][1] = __builtin_amdgcn_mfma_f32_16x16x32_bf16(a0, b1, acc[0][1], 0, 0, 0);
        acc[1][1] = __builtin_amdgcn_mfma_f32_16x16x32_bf16(a1, b1, acc[1][1], 0, 0, 0);
        acc[0][2] = __builtin_amdgcn_mfma_f32_16x16x32_bf16(a0, b2, acc[0][2], 0, 0, 0);
        acc[1][2] = __builtin_amdgcn_mfma_f32_16x16x32_bf16(a1, b2, acc[1][2], 0, 0, 0);
        acc[0][3] = __builtin_amdgcn_mfma_f32_16x16x32_bf16(a0, b3, acc[0][3], 0, 0, 0);
        acc[1][3] = __builtin_amdgcn_mfma_f32_16x16x32_bf16(a1, b3, acc[1][3], 0, 0, 0);

        // ---- own-wave fence for next body's LDS reads. NO barrier.
        if (k < K_OFF - 1) {
            if      (k == 0)  FENCE_VM(8);
            else if (k <= 22) FENCE_VM(10);
            else if (k == 23) FENCE_VM(8);
            else if (k == 24) FENCE_VM(6);
            else              FENCE_VM(0);
        }
    }

    // epilogue: C/D layout col=lane&15, row=q*4+reg
    #pragma unroll
    for (int rt = 0; rt < 2; ++rt)
        #pragma unroll
        for (int ct = 0; ct < 4; ++ct)
            #pragma unroll
            for (int r = 0; r < 4; ++r) {
                const int row = n0 + rt * 16 + q * 4 + r;
                if (row < n) out[(size_t)row * COUT + ct * 16 + lrow] = acc[rt][ct][r];
            }
}

// ---------------------------------------------------------------------------
// fp32 fallback path (only if ws too small for bf16 staging).
// ---------------------------------------------------------------------------
__global__ __launch_bounds__(256) void detect_mask(
    const unsigned char* __restrict__ mask, int nbytes, int* __restrict__ flag,
    float* __restrict__ zrow) {
    __shared__ int wany[4];
    int found = 0;
    for (int i = threadIdx.x; i < nbytes; i += 256)
        if ((i & 3) && mask[i]) found = 1;
    unsigned long long b = __ballot(found);
    if ((threadIdx.x & 63) == 0) wany[threadIdx.x >> 6] = b ? 1 : 0;
    __syncthreads();
    if (threadIdx.x == 0) *flag = wany[0] | wany[1] | wany[2] | wany[3];
    if (threadIdx.x < 16) zrow[threadIdx.x] = 0.0f;
}

#define BN 64
__global__ __launch_bounds__(256) void sparse_conv_fp32(
    const float* __restrict__ feat, const int* __restrict__ nmap,
    const unsigned char* __restrict__ mask8, const int* __restrict__ mask32,
    const float* __restrict__ wk, float* __restrict__ out,
    int n, const int* __restrict__ flag)
{
    __shared__ float A[CIN][BN];
    __shared__ float W[CIN][COUT];
    const int tid = threadIdx.x;
    const int n0 = blockIdx.x * BN;
    const int is_b8 = *flag;
    const int r0 = (tid >> 4) * 4, c0 = (tid & 15) * 4;
    const int grow = tid >> 2, gpart = tid & 3;
    float acc[4][4] = {};
    for (int k = 0; k < K_OFF; ++k) {
        {
            const int base = tid * 8;
            const float* wsrc = wk + (size_t)k * (CIN * COUT) + base;
            float4 w0 = ((const float4*)wsrc)[0];
            float4 w1 = ((const float4*)wsrc)[1];
            *(float4*)&W[base >> 6][base & 63] = w0;
            *(float4*)&W[base >> 6][(base & 63) + 4] = w1;
        }
        {
            const int gn = n0 + grow;
            float4 f0 = make_float4(0.f, 0.f, 0.f, 0.f), f1 = f0;
            if (gn < n) {
                const int idx = k * n + gn;
                const int m = is_b8 ? (int)mask8[idx] : mask32[idx];
                if (m) {
                    const float* fsrc = feat + (size_t)nmap[idx] * CIN + gpart * 8;
                    f0 = ((const float4*)fsrc)[0];
                    f1 = ((const float4*)fsrc)[1];
                }
            }
            const int cb = gpart * 8;
            A[cb+0][grow]=f0.x; A[cb+1][grow]=f0.y; A[cb+2][grow]=f0.z; A[cb+3][grow]=f0.w;
            A[cb+4][grow]=f1.x; A[cb+5][grow]=f1.y; A[cb+6][grow]=f1.z; A[cb+7][grow]=f1.w;
        }
        __syncthreads();
        #pragma unroll
        for (int c = 0; c < CIN; ++c) {
            const float4 a = *(const float4*)&A[c][r0];
            const float4 w = *(const float4*)&W[c][c0];
            acc[0][0]+=a.x*w.x; acc[0][1]+=a.x*w.y; acc[0][2]+=a.x*w.z; acc[0][3]+=a.x*w.w;
            acc[1][0]+=a.y*w.x; acc[1][1]+=a.y*w.y; acc[1][2]+=a.y*w.z; acc[1][3]+=a.y*w.w;
            acc[2][0]+=a.z*w.x; acc[2][1]+=a.z*w.y; acc[2][2]+=a.z*w.z; acc[2][3]+=a.z*w.w;
            acc[3][0]+=a.w*w.x; acc[3][1]+=a.w*w.y; acc[3][2]+=a.w*w.z; acc[3][3]+=a.w*w.w;
        }
        __syncthreads();
    }
    #pragma unroll
    for (int i = 0; i < 4; ++i) {
        const int orow = n0 + r0 + i;
        if (orow < n)
            *(float4*)&out[(size_t)orow * COUT + c0] =
                make_float4(acc[i][0], acc[i][1], acc[i][2], acc[i][3]);
    }
}

static inline size_t align16(size_t x) { return (x + 15) & ~(size_t)15; }

extern "C" void kernel_launch(void* const* d_in, const int* in_sizes, int n_in,
                              void* d_out, int out_size, void* d_ws, size_t ws_size,
                              hipStream_t stream) {
    const float*         feat = (const float*)d_in[0];
    const int*           nmap = (const int*)d_in[1];
    const unsigned char* m8   = (const unsigned char*)d_in[2];
    const int*           m32  = (const int*)d_in[2];
    const float*         wk   = (const float*)d_in[3];
    float*               out  = (float*)d_out;

    const int n = in_sizes[0] / CIN;
    int*   flag = (int*)d_ws;
    float* zrow = (float*)((char*)d_ws + 64);       // 64B zero row

    const size_t feat_off   = 128;
    const size_t feat_bytes = (size_t)n * CIN * 2;
    const size_t midx_off   = align16(feat_off + feat_bytes);
    const size_t midx_bytes = (size_t)K_OFF * n * 4;
    const size_t wt2_off    = align16(midx_off + midx_bytes);
    const size_t wt2_bytes  = (size_t)K_OFF * 4 * 64 * 8 * 2;
    const size_t needed     = wt2_off + wt2_bytes;

    const int mask_elems = K_OFF * n;
    const int det_bytes  = mask_elems < 4096 ? mask_elems : 4096;

    if (ws_size >= needed) {
        unsigned short* featb = (unsigned short*)((char*)d_ws + feat_off);
        int*            midx  = (int*)((char*)d_ws + midx_off);
        unsigned short* wt2   = (unsigned short*)((char*)d_ws + wt2_off);

        prep_all<<<2048, 256, 0, stream>>>(
            feat, nmap, m8, wk, featb, midx, wt2, zrow, n, det_bytes);

        const int ntiles = (n + 127) / 128;
        conv_mfma15<<<ntiles, 256, 0, stream>>>(
            featb, midx, wt2, (const unsigned short*)zrow, out, n);
    } else {
        detect_mask<<<1, 256, 0, stream>>>(m8, det_bytes, flag, zrow);
        const int nb = (n + BN - 1) / BN;
        sparse_conv_fp32<<<nb, 256, 0, stream>>>(feat, nmap, m8, m32, wk, out, n, flag);
    }
}

// Round 10
// 167.477 us; speedup vs baseline: 1.2878x; 1.2878x over previous
//
#include <hip/hip_runtime.h>

#define CIN   32
#define COUT  64
#define K_OFF 27

typedef __attribute__((ext_vector_type(8))) short bf16x8;
typedef __attribute__((ext_vector_type(4))) float f32x4;

// exact vmcnt fence + compiler memory pin (defines VMEM issue order)
#define FENCE_VM(N) asm volatile("s_waitcnt vmcnt(" #N ")" ::: "memory")
#define PIN()       asm volatile("" ::: "memory")
#define BARRIER()   asm volatile("s_barrier" ::: "memory")

__device__ inline unsigned short f2bf_rne(float f) {
    union { float f; unsigned int u; } v; v.f = f;
    unsigned int u = v.u;
    u = (u + 0x7fffu + ((u >> 16) & 1u)) >> 16;
    return (unsigned short)u;
}

// async 16B global -> LDS (per-lane src addr; LDS dest = wave-uniform base
// + lane*16). Completion signaled via vmcnt — fenced by hand.
__device__ inline void async_load16(const void* g, void* l) {
    __builtin_amdgcn_global_load_lds(
        (const __attribute__((address_space(1))) void*)g,
        (__attribute__((address_space(3))) void*)l, 16, 0, 0);
}

// ===========================================================================
// prep_all — ONE grid-stride kernel (banked R7): per-block mask-dtype detect;
// feat fp32->bf16; midx; wt2 repack; zrow.
// ===========================================================================
__global__ __launch_bounds__(256) void prep_all(
    const float* __restrict__ feat, const int* __restrict__ nmap,
    const unsigned char* __restrict__ mask8, const float* __restrict__ wk,
    unsigned short* __restrict__ featb, int* __restrict__ midx,
    unsigned short* __restrict__ wt2, float* __restrict__ zrow,
    int n, int det_bytes)
{
    __shared__ int wany[4];
    const int tid = threadIdx.x;
    const int gsz = gridDim.x * 256;
    const int gt  = blockIdx.x * 256 + tid;

    // per-block detect: nonzero byte at a non-dword-aligned offset => b8 mask
    {
        int found = 0;
        for (int i = tid; i < det_bytes; i += 256)
            if ((i & 3) && mask8[i]) found = 1;
        unsigned long long b = __ballot(found);
        if ((tid & 63) == 0) wany[tid >> 6] = b ? 1 : 0;
        __syncthreads();
    }
    const int is_b8 = wany[0] | wany[1] | wany[2] | wany[3];

    // feat fp32 -> bf16
    const int F = (n * CIN) / 8;
    for (int i = gt; i < F; i += gsz) {
        const int base = i * 8;
        float4 a = *(const float4*)(feat + base);
        float4 b = *(const float4*)(feat + base + 4);
        bf16x8 v;
        v[0] = (short)f2bf_rne(a.x); v[1] = (short)f2bf_rne(a.y);
        v[2] = (short)f2bf_rne(a.z); v[3] = (short)f2bf_rne(a.w);
        v[4] = (short)f2bf_rne(b.x); v[5] = (short)f2bf_rne(b.y);
        v[6] = (short)f2bf_rne(b.z); v[7] = (short)f2bf_rne(b.w);
        *(bf16x8*)(featb + base) = v;
    }

    // midx = mask ? nmap : -1
    {
        const int total = K_OFF * n;
        const int Q = (total + 3) / 4;
        for (int i = gt; i < Q; i += gsz) {
            int e = i * 4;
            if (e + 3 < total) {
                int4 nm = *(const int4*)(nmap + e);
                int m0, m1, m2, m3;
                if (is_b8) {
                    uchar4 mb = *(const uchar4*)(mask8 + e);
                    m0 = mb.x; m1 = mb.y; m2 = mb.z; m3 = mb.w;
                } else {
                    const int* m32 = (const int*)mask8;
                    int4 mm = *(const int4*)(m32 + e);
                    m0 = mm.x; m1 = mm.y; m2 = mm.z; m3 = mm.w;
                }
                int4 r;
                r.x = m0 ? nm.x : -1; r.y = m1 ? nm.y : -1;
                r.z = m2 ? nm.z : -1; r.w = m3 ? nm.w : -1;
                *(int4*)(midx + e) = r;
            } else {
                for (; e < total; ++e) {
                    int m = is_b8 ? (int)mask8[e] : ((const int*)mask8)[e];
                    midx[e] = m ? nmap[e] : -1;
                }
            }
        }
    }

    // weights -> fragment-order bf16 wt2[k][ct][lane][8]
    for (int t = gt; t < K_OFF * 4 * 64; t += gsz) {
        const int lane = t & 63, ct = (t >> 6) & 3, k = t >> 8;
        const int lrow = lane & 15, q = lane >> 4;
        const int col = ct * 16 + lrow;
        bf16x8 v;
        #pragma unroll
        for (int j = 0; j < 8; ++j)
            v[j] = (short)f2bf_rne(wk[(k * CIN + q * 8 + j) * COUT + col]);
        *(bf16x8*)(wt2 + t * 8) = v;
    }

    if (gt < 16) zrow[gt] = 0.0f;
}

// ---------------------------------------------------------------------------
// conv_mfma16 — 8 waves x 16 rows (512-thread block, SAME 128-row tile).
// R8/R9 lessons: (a) resident WAVES are the latency-hiding resource (R8:
// halving static waves/CU 16->8 cost ~proportionally); (b) block-shared B
// staging + barrier lockstep are load-bearing (R9: per-wave B regs = 2x
// worse, FETCH/WRITE ballooned). This kernel keeps per-block traffic, VMEM
// instruction count, LDS bytes (36KB) and the B-staging structure IDENTICAL
// to conv_mfma10 — but splits the same work over 2x the waves (each: 1
// gather, 1 M-load, 4 MFMA per body). Static occupancy: 4 blocks x 8 waves
// = 32 waves/CU (vs 16). Prediction: exposed gather stall halves.
// B staged by waves 0-3 only (quarter = wave). Two wave-uniform fence
// tables (outstanding-set walk):
//   group A (w0-3), per body issues [B(k+2)][G(k+2)][M(k+4)]:
//     prologue M0..3,B0,B1,G0,G1 -> VM(1) (G1 in flight).
//     k=0: retire G1 -> younger B2,G2,M4 = 3.  k=1..22: retire B(k+1),G(k+1)
//     -> younger M(k+3)+body k's 3 = 4.  k=23: 3.  k=24: 2.  k=25: 0.
//   group B (w4-7), per body issues [G(k+2)][M(k+4)]:
//     prologue M0..3,G0,G1 -> VM(1).
//     k=0: 2.  k=1..22: 3.  k=23: 2.  k=24: 1.  k=25: 0.
// s_barrier after each group's own fence => all LDS slices valid block-wide.
// ---------------------------------------------------------------------------
__global__ __launch_bounds__(512) void conv_mfma16(
    const unsigned short* __restrict__ featb,   // [N][CIN] bf16
    const int*            __restrict__ midx,    // [K][N] fused mask?nmap:-1
    const unsigned short* __restrict__ wt2,     // fragment-order weights
    const unsigned short* __restrict__ zrow,    // 64B of zeros
    float* __restrict__ out, int n)
{
    __shared__ __attribute__((aligned(16))) unsigned short Bs[3][4][512];    // 12 KB
    __shared__ __attribute__((aligned(16))) unsigned short As[3][8][512];    // 24 KB

    const int tid  = threadIdx.x;
    const int wave = tid >> 6;          // 0..7
    const int lane = tid & 63;
    const int lrow = lane & 15;
    const int q    = lane >> 4;
    const int n0   = blockIdx.x * 128;
    const int wr   = n0 + wave * 16;    // this wave's 16-row base

    const int  row  = wr + lrow;
    const bool vrow = row < n;

    auto load_mi = [&](int k) -> int {
        if (!vrow) return -1;
        return midx[k * n + row];
    };
    auto issue_gather = [&](int mi, unsigned short* ldsbase) {
        const unsigned short* src =
            (mi >= 0) ? featb + (size_t)mi * CIN + q * 8 : zrow;
        async_load16(src, ldsbase);
    };
    auto stageB = [&](int k) {   // waves 0-3: quarter = wave, of slice k
        const unsigned short* src = wt2 + (((k * 4 + wave)) << 9) + lane * 8;
        async_load16(src, &Bs[k % 3][wave][0]);
    };

    int   mi_buf[2];
    f32x4 acc[4] = {};

    // ---- prologue: M(0..3); [w0-3] B(0),B(1); G(0),G(1). VM(1): G(1) fly.
    {
        int p0 = load_mi(0), p1 = load_mi(1);
        mi_buf[0] = load_mi(2); mi_buf[1] = load_mi(3);
        PIN();
        if (wave < 4) { stageB(0); stageB(1); }
        PIN();
        issue_gather(p0, &As[0][wave][0]);
        PIN();
        issue_gather(p1, &As[1][wave][0]);
        PIN();
        FENCE_VM(1);
        BARRIER();
    }

    #pragma unroll
    for (int k = 0; k < K_OFF; ++k) {
        // ---- consume LDS (fenced+barriered at end of previous body)
        bf16x8 a0 = *(const bf16x8*)(&As[k % 3][wave][lane * 8]);
        bf16x8 b0 = *(const bf16x8*)(&Bs[k % 3][0][lane * 8]);
        bf16x8 b1 = *(const bf16x8*)(&Bs[k % 3][1][lane * 8]);
        bf16x8 b2 = *(const bf16x8*)(&Bs[k % 3][2][lane * 8]);
        bf16x8 b3 = *(const bf16x8*)(&Bs[k % 3][3][lane * 8]);
        PIN();

        // ---- prefetch issues (pinned order: [B] G M)
        if (k + 2 < K_OFF) {
            if (wave < 4) { stageB(k + 2); }
            PIN();
            issue_gather(mi_buf[k & 1], &As[(k + 2) % 3][wave][0]);
            PIN();
        }
        if (k + 4 < K_OFF) {
            mi_buf[k & 1] = load_mi(k + 4);
            PIN();
        }

        // ---- 4 MFMA (16 rows x 64 couts)
        acc[0] = __builtin_amdgcn_mfma_f32_16x16x32_bf16(a0, b0, acc[0], 0, 0, 0);
        acc[1] = __builtin_amdgcn_mfma_f32_16x16x32_bf16(a0, b1, acc[1], 0, 0, 0);
        acc[2] = __builtin_amdgcn_mfma_f32_16x16x32_bf16(a0, b2, acc[2], 0, 0, 0);
        acc[3] = __builtin_amdgcn_mfma_f32_16x16x32_bf16(a0, b3, acc[3], 0, 0, 0);

        // ---- fence own prefetches (group-specific), then block barrier
        if (k < K_OFF - 1) {
            if (wave < 4) {
                if      (k == 0)  FENCE_VM(3);
                else if (k <= 22) FENCE_VM(4);
                else if (k == 23) FENCE_VM(3);
                else if (k == 24) FENCE_VM(2);
                else              FENCE_VM(0);
            } else {
                if      (k == 0)  FENCE_VM(2);
                else if (k <= 22) FENCE_VM(3);
                else if (k == 23) FENCE_VM(2);
                else if (k == 24) FENCE_VM(1);
                else              FENCE_VM(0);
            }
            BARRIER();
        }
    }

    // epilogue: C/D layout col=lane&15, row=q*4+reg (within this wave's tile)
    #pragma unroll
    for (int ct = 0; ct < 4; ++ct)
        #pragma unroll
        for (int r = 0; r < 4; ++r) {
            const int orow = wr + q * 4 + r;
            if (orow < n) out[(size_t)orow * COUT + ct * 16 + lrow] = acc[ct][r];
        }
}

// ---------------------------------------------------------------------------
// fp32 fallback path (only if ws too small for bf16 staging).
// ---------------------------------------------------------------------------
__global__ __launch_bounds__(256) void detect_mask(
    const unsigned char* __restrict__ mask, int nbytes, int* __restrict__ flag,
    float* __restrict__ zrow) {
    __shared__ int wany[4];
    int found = 0;
    for (int i = threadIdx.x; i < nbytes; i += 256)
        if ((i & 3) && mask[i]) found = 1;
    unsigned long long b = __ballot(found);
    if ((threadIdx.x & 63) == 0) wany[threadIdx.x >> 6] = b ? 1 : 0;
    __syncthreads();
    if (threadIdx.x == 0) *flag = wany[0] | wany[1] | wany[2] | wany[3];
    if (threadIdx.x < 16) zrow[threadIdx.x] = 0.0f;
}

#define BN 64
__global__ __launch_bounds__(256) void sparse_conv_fp32(
    const float* __restrict__ feat, const int* __restrict__ nmap,
    const unsigned char* __restrict__ mask8, const int* __restrict__ mask32,
    const float* __restrict__ wk, float* __restrict__ out,
    int n, const int* __restrict__ flag)
{
    __shared__ float A[CIN][BN];
    __shared__ float W[CIN][COUT];
    const int tid = threadIdx.x;
    const int n0 = blockIdx.x * BN;
    const int is_b8 = *flag;
    const int r0 = (tid >> 4) * 4, c0 = (tid & 15) * 4;
    const int grow = tid >> 2, gpart = tid & 3;
    float acc[4][4] = {};
    for (int k = 0; k < K_OFF; ++k) {
        {
            const int base = tid * 8;
            const float* wsrc = wk + (size_t)k * (CIN * COUT) + base;
            float4 w0 = ((const float4*)wsrc)[0];
            float4 w1 = ((const float4*)wsrc)[1];
            *(float4*)&W[base >> 6][base & 63] = w0;
            *(float4*)&W[base >> 6][(base & 63) + 4] = w1;
        }
        {
            const int gn = n0 + grow;
            float4 f0 = make_float4(0.f, 0.f, 0.f, 0.f), f1 = f0;
            if (gn < n) {
                const int idx = k * n + gn;
                const int m = is_b8 ? (int)mask8[idx] : mask32[idx];
                if (m) {
                    const float* fsrc = feat + (size_t)nmap[idx] * CIN + gpart * 8;
                    f0 = ((const float4*)fsrc)[0];
                    f1 = ((const float4*)fsrc)[1];
                }
            }
            const int cb = gpart * 8;
            A[cb+0][grow]=f0.x; A[cb+1][grow]=f0.y; A[cb+2][grow]=f0.z; A[cb+3][grow]=f0.w;
            A[cb+4][grow]=f1.x; A[cb+5][grow]=f1.y; A[cb+6][grow]=f1.z; A[cb+7][grow]=f1.w;
        }
        __syncthreads();
        #pragma unroll
        for (int c = 0; c < CIN; ++c) {
            const float4 a = *(const float4*)&A[c][r0];
            const float4 w = *(const float4*)&W[c][c0];
            acc[0][0]+=a.x*w.x; acc[0][1]+=a.x*w.y; acc[0][2]+=a.x*w.z; acc[0][3]+=a.x*w.w;
            acc[1][0]+=a.y*w.x; acc[1][1]+=a.y*w.y; acc[1][2]+=a.y*w.z; acc[1][3]+=a.y*w.w;
            acc[2][0]+=a.z*w.x; acc[2][1]+=a.z*w.y; acc[2][2]+=a.z*w.z; acc[2][3]+=a.z*w.w;
            acc[3][0]+=a.w*w.x; acc[3][1]+=a.w*w.y; acc[3][2]+=a.w*w.z; acc[3][3]+=a.w*w.w;
        }
        __syncthreads();
    }
    #pragma unroll
    for (int i = 0; i < 4; ++i) {
        const int orow = n0 + r0 + i;
        if (orow < n)
            *(float4*)&out[(size_t)orow * COUT + c0] =
                make_float4(acc[i][0], acc[i][1], acc[i][2], acc[i][3]);
    }
}

static inline size_t align16(size_t x) { return (x + 15) & ~(size_t)15; }

extern "C" void kernel_launch(void* const* d_in, const int* in_sizes, int n_in,
                              void* d_out, int out_size, void* d_ws, size_t ws_size,
                              hipStream_t stream) {
    const float*         feat = (const float*)d_in[0];
    const int*           nmap = (const int*)d_in[1];
    const unsigned char* m8   = (const unsigned char*)d_in[2];
    const int*           m32  = (const int*)d_in[2];
    const float*         wk   = (const float*)d_in[3];
    float*               out  = (float*)d_out;

    const int n = in_sizes[0] / CIN;
    int*   flag = (int*)d_ws;
    float* zrow = (float*)((char*)d_ws + 64);       // 64B zero row

    const size_t feat_off   = 128;
    const size_t feat_bytes = (size_t)n * CIN * 2;
    const size_t midx_off   = align16(feat_off + feat_bytes);
    const size_t midx_bytes = (size_t)K_OFF * n * 4;
    const size_t wt2_off    = align16(midx_off + midx_bytes);
    const size_t wt2_bytes  = (size_t)K_OFF * 4 * 64 * 8 * 2;
    const size_t needed     = wt2_off + wt2_bytes;

    const int mask_elems = K_OFF * n;
    const int det_bytes  = mask_elems < 4096 ? mask_elems : 4096;

    if (ws_size >= needed) {
        unsigned short* featb = (unsigned short*)((char*)d_ws + feat_off);
        int*            midx  = (int*)((char*)d_ws + midx_off);
        unsigned short* wt2   = (unsigned short*)((char*)d_ws + wt2_off);

        prep_all<<<2048, 256, 0, stream>>>(
            feat, nmap, m8, wk, featb, midx, wt2, zrow, n, det_bytes);

        const int ntiles = (n + 127) / 128;
        conv_mfma16<<<ntiles, 512, 0, stream>>>(
            featb, midx, wt2, (const unsigned short*)zrow, out, n);
    } else {
        detect_mask<<<1, 256, 0, stream>>>(m8, det_bytes, flag, zrow);
        const int nb = (n + BN - 1) / BN;
        sparse_conv_fp32<<<nb, 256, 0, stream>>>(feat, nmap, m8, m32, wk, out, n, flag);
    }
}